// Round 1
// baseline (2942.144 us; speedup 1.0000x reference)
//
#include <hip/hip_runtime.h>

#define NN 50000
#define NE 600000

__device__ __forceinline__ float silu_f(float x) { return x / (1.0f + __expf(-x)); }

// ---------------------------------------------------------------------------
// K1: t1 = silu([h[row], h[col], radial] @ w_e1 + b_e1)          [E,128]
// t1 is written into the edge_feat output region (temp storage; K2 overwrites
// it in-place with the real edge_feat).
// Block: 256 thr = 4 waves; each wave processes 4 edges per group iteration.
// w_e1 (257x128 fp32 = 131.6 KB) staged in LDS once per block.
// ---------------------------------------------------------------------------
__global__ __launch_bounds__(256) void k_edge_l1(
    const float* __restrict__ h, const float* __restrict__ coord,
    const int* __restrict__ ei, const float* __restrict__ w_e1,
    const float* __restrict__ b_e1, float* __restrict__ t1)
{
    __shared__ float wl[257 * 128];      // 131584 B
    __shared__ float ein[4][257][4];     // 16448 B  (inputs interleaved [k][edge])
    const int tid = threadIdx.x;
    for (int i = tid; i < 257 * 128; i += 256) wl[i] = w_e1[i];
    const int wv = tid >> 6, ln = tid & 63;
    const float b0 = b_e1[ln], b1 = b_e1[ln + 64];
    __syncthreads();

    const int ngroups = NE / 16;         // 37500 exactly
    for (int g = blockIdx.x; g < ngroups; g += gridDim.x) {
        const int ebase = g * 16 + wv * 4;
        #pragma unroll
        for (int e = 0; e < 4; ++e) {
            const int eid = ebase + e;
            const int r = ei[eid], c = ei[NE + eid];
            ein[wv][ln][e]       = h[r * 128 + ln];
            ein[wv][64 + ln][e]  = h[r * 128 + 64 + ln];
            ein[wv][128 + ln][e] = h[c * 128 + ln];
            ein[wv][192 + ln][e] = h[c * 128 + 64 + ln];
        }
        if (ln < 4) {
            const int eid = ebase + ln;
            const int r = ei[eid], c = ei[NE + eid];
            const float dx = coord[r * 3 + 0] - coord[c * 3 + 0];
            const float dy = coord[r * 3 + 1] - coord[c * 3 + 1];
            const float dz = coord[r * 3 + 2] - coord[c * 3 + 2];
            ein[wv][256][ln] = dx * dx + dy * dy + dz * dz;
        }
        __syncthreads();

        float a00 = b0, a01 = b1, a10 = b0, a11 = b1;
        float a20 = b0, a21 = b1, a30 = b0, a31 = b1;
        for (int k = 0; k < 257; ++k) {
            const float4 iv = *(const float4*)&ein[wv][k][0];  // broadcast
            const float w0 = wl[k * 128 + ln];
            const float w1 = wl[k * 128 + 64 + ln];
            a00 += iv.x * w0; a01 += iv.x * w1;
            a10 += iv.y * w0; a11 += iv.y * w1;
            a20 += iv.z * w0; a21 += iv.z * w1;
            a30 += iv.w * w0; a31 += iv.w * w1;
        }
        t1[(ebase + 0) * 128 + ln]      = silu_f(a00);
        t1[(ebase + 0) * 128 + 64 + ln] = silu_f(a01);
        t1[(ebase + 1) * 128 + ln]      = silu_f(a10);
        t1[(ebase + 1) * 128 + 64 + ln] = silu_f(a11);
        t1[(ebase + 2) * 128 + ln]      = silu_f(a20);
        t1[(ebase + 2) * 128 + 64 + ln] = silu_f(a21);
        t1[(ebase + 3) * 128 + ln]      = silu_f(a30);
        t1[(ebase + 3) * 128 + 64 + ln] = silu_f(a31);
    }
}

// ---------------------------------------------------------------------------
// K2: edge_feat = silu(t1 @ w_e2 + b_e2)            (write to out, in-place)
//     c1        = silu(edge_feat @ w_c1 + b_c1)
//     wq        = c1 @ w_c2                          (scalar per edge)
//     atomics:  agg[row]  += edge_feat
//               tsum[row] += coord_diff * wq ;  cnt[row] += 1
// ---------------------------------------------------------------------------
__global__ __launch_bounds__(256) void k_edge_l2(
    const float* __restrict__ coord, const int* __restrict__ ei,
    const float* __restrict__ w_e2, const float* __restrict__ b_e2,
    const float* __restrict__ w_c1, const float* __restrict__ b_c1,
    const float* __restrict__ w_c2,
    float* __restrict__ ef,          // in: t1, out: edge_feat (same buffer)
    float* __restrict__ agg, float* __restrict__ tsum, float* __restrict__ cnt)
{
    __shared__ float w2l[128 * 128];     // 65536 B
    __shared__ float wc1l[128 * 128];    // 65536 B
    __shared__ float wc2l[128];          // 512 B
    __shared__ float tin[4][128][4];     // 8192 B
    __shared__ float efs[4][128][4];     // 8192 B
    const int tid = threadIdx.x;
    for (int i = tid; i < 128 * 128; i += 256) { w2l[i] = w_e2[i]; wc1l[i] = w_c1[i]; }
    if (tid < 128) wc2l[tid] = w_c2[tid];
    const int wv = tid >> 6, ln = tid & 63;
    const float be0 = b_e2[ln], be1 = b_e2[ln + 64];
    const float bc0 = b_c1[ln], bc1 = b_c1[ln + 64];
    __syncthreads();

    const int ngroups = NE / 16;
    for (int g = blockIdx.x; g < ngroups; g += gridDim.x) {
        const int ebase = g * 16 + wv * 4;
        #pragma unroll
        for (int e = 0; e < 4; ++e) {
            const int eid = ebase + e;
            tin[wv][ln][e]      = ef[eid * 128 + ln];
            tin[wv][64 + ln][e] = ef[eid * 128 + 64 + ln];
        }
        __syncthreads();

        // layer e2
        float a00 = be0, a01 = be1, a10 = be0, a11 = be1;
        float a20 = be0, a21 = be1, a30 = be0, a31 = be1;
        for (int k = 0; k < 128; ++k) {
            const float4 iv = *(const float4*)&tin[wv][k][0];
            const float w0 = w2l[k * 128 + ln];
            const float w1 = w2l[k * 128 + 64 + ln];
            a00 += iv.x * w0; a01 += iv.x * w1;
            a10 += iv.y * w0; a11 += iv.y * w1;
            a20 += iv.z * w0; a21 += iv.z * w1;
            a30 += iv.w * w0; a31 += iv.w * w1;
        }
        float v[4][2];
        v[0][0] = silu_f(a00); v[0][1] = silu_f(a01);
        v[1][0] = silu_f(a10); v[1][1] = silu_f(a11);
        v[2][0] = silu_f(a20); v[2][1] = silu_f(a21);
        v[3][0] = silu_f(a30); v[3][1] = silu_f(a31);
        #pragma unroll
        for (int e = 0; e < 4; ++e) {
            const int eid = ebase + e;
            const int r = ei[eid];
            ef[eid * 128 + ln]      = v[e][0];
            ef[eid * 128 + 64 + ln] = v[e][1];
            efs[wv][ln][e]      = v[e][0];
            efs[wv][64 + ln][e] = v[e][1];
            atomicAdd(&agg[r * 128 + ln],      v[e][0]);
            atomicAdd(&agg[r * 128 + 64 + ln], v[e][1]);
        }

        // layer c1
        float c00 = bc0, c01 = bc1, c10 = bc0, c11 = bc1;
        float c20 = bc0, c21 = bc1, c30 = bc0, c31 = bc1;
        for (int k = 0; k < 128; ++k) {
            const float4 iv = *(const float4*)&efs[wv][k][0];
            const float w0 = wc1l[k * 128 + ln];
            const float w1 = wc1l[k * 128 + 64 + ln];
            c00 += iv.x * w0; c01 += iv.x * w1;
            c10 += iv.y * w0; c11 += iv.y * w1;
            c20 += iv.z * w0; c21 += iv.z * w1;
            c30 += iv.w * w0; c31 += iv.w * w1;
        }
        // layer c2: per-edge scalar; wave reduce
        float cc[4][2] = {{c00,c01},{c10,c11},{c20,c21},{c30,c31}};
        float wq = 0.0f;
        #pragma unroll
        for (int e = 0; e < 4; ++e) {
            float p = silu_f(cc[e][0]) * wc2l[ln] + silu_f(cc[e][1]) * wc2l[64 + ln];
            #pragma unroll
            for (int off = 1; off < 64; off <<= 1) p += __shfl_xor(p, off);
            if (ln == e) wq = p;
        }
        if (ln < 4) {
            const int eid = ebase + ln;
            const int r = ei[eid], c = ei[NE + eid];
            const float dx = coord[r * 3 + 0] - coord[c * 3 + 0];
            const float dy = coord[r * 3 + 1] - coord[c * 3 + 1];
            const float dz = coord[r * 3 + 2] - coord[c * 3 + 2];
            atomicAdd(&tsum[r * 3 + 0], dx * wq);
            atomicAdd(&tsum[r * 3 + 1], dy * wq);
            atomicAdd(&tsum[r * 3 + 2], dz * wq);
            atomicAdd(&cnt[r], 1.0f);
        }
    }
}

// ---------------------------------------------------------------------------
// K3a: u = silu([h, agg] @ w_n1 + b_n1)                      [N,128]
// ---------------------------------------------------------------------------
__global__ __launch_bounds__(256) void k_node_l1(
    const float* __restrict__ h, const float* __restrict__ agg,
    const float* __restrict__ w_n1, const float* __restrict__ b_n1,
    float* __restrict__ u)
{
    __shared__ float wl[256 * 128];      // 131072 B
    __shared__ float nin[4][256][4];     // 16384 B
    const int tid = threadIdx.x;
    for (int i = tid; i < 256 * 128; i += 256) wl[i] = w_n1[i];
    const int wv = tid >> 6, ln = tid & 63;
    const float b0 = b_n1[ln], b1 = b_n1[ln + 64];
    __syncthreads();

    const int ngroups = NN / 16;         // 3125 exactly
    for (int g = blockIdx.x; g < ngroups; g += gridDim.x) {
        const int nbase = g * 16 + wv * 4;
        #pragma unroll
        for (int e = 0; e < 4; ++e) {
            const int n = nbase + e;
            nin[wv][ln][e]       = h[n * 128 + ln];
            nin[wv][64 + ln][e]  = h[n * 128 + 64 + ln];
            nin[wv][128 + ln][e] = agg[n * 128 + ln];
            nin[wv][192 + ln][e] = agg[n * 128 + 64 + ln];
        }
        __syncthreads();

        float a00 = b0, a01 = b1, a10 = b0, a11 = b1;
        float a20 = b0, a21 = b1, a30 = b0, a31 = b1;
        for (int k = 0; k < 256; ++k) {
            const float4 iv = *(const float4*)&nin[wv][k][0];
            const float w0 = wl[k * 128 + ln];
            const float w1 = wl[k * 128 + 64 + ln];
            a00 += iv.x * w0; a01 += iv.x * w1;
            a10 += iv.y * w0; a11 += iv.y * w1;
            a20 += iv.z * w0; a21 += iv.z * w1;
            a30 += iv.w * w0; a31 += iv.w * w1;
        }
        u[(nbase + 0) * 128 + ln]      = silu_f(a00);
        u[(nbase + 0) * 128 + 64 + ln] = silu_f(a01);
        u[(nbase + 1) * 128 + ln]      = silu_f(a10);
        u[(nbase + 1) * 128 + 64 + ln] = silu_f(a11);
        u[(nbase + 2) * 128 + ln]      = silu_f(a20);
        u[(nbase + 2) * 128 + 64 + ln] = silu_f(a21);
        u[(nbase + 3) * 128 + ln]      = silu_f(a30);
        u[(nbase + 3) * 128 + 64 + ln] = silu_f(a31);
    }
}

// ---------------------------------------------------------------------------
// K3b: h_new = h + u @ w_n2 + b_n2 ;  coord_new = coord + tsum / max(cnt,1)
// ---------------------------------------------------------------------------
__global__ __launch_bounds__(256) void k_node_l2(
    const float* __restrict__ h, const float* __restrict__ u,
    const float* __restrict__ w_n2, const float* __restrict__ b_n2,
    const float* __restrict__ coord, const float* __restrict__ tsum,
    const float* __restrict__ cnt,
    float* __restrict__ h_new, float* __restrict__ coord_new)
{
    __shared__ float wl[128 * 128];      // 65536 B
    __shared__ float nin[4][128][4];     // 8192 B
    const int tid = threadIdx.x;
    for (int i = tid; i < 128 * 128; i += 256) wl[i] = w_n2[i];
    const int wv = tid >> 6, ln = tid & 63;
    const float b0 = b_n2[ln], b1 = b_n2[ln + 64];
    __syncthreads();

    const int ngroups = NN / 16;
    for (int g = blockIdx.x; g < ngroups; g += gridDim.x) {
        const int nbase = g * 16 + wv * 4;
        #pragma unroll
        for (int e = 0; e < 4; ++e) {
            const int n = nbase + e;
            nin[wv][ln][e]      = u[n * 128 + ln];
            nin[wv][64 + ln][e] = u[n * 128 + 64 + ln];
        }
        __syncthreads();

        float a00 = b0, a01 = b1, a10 = b0, a11 = b1;
        float a20 = b0, a21 = b1, a30 = b0, a31 = b1;
        for (int k = 0; k < 128; ++k) {
            const float4 iv = *(const float4*)&nin[wv][k][0];
            const float w0 = wl[k * 128 + ln];
            const float w1 = wl[k * 128 + 64 + ln];
            a00 += iv.x * w0; a01 += iv.x * w1;
            a10 += iv.y * w0; a11 += iv.y * w1;
            a20 += iv.z * w0; a21 += iv.z * w1;
            a30 += iv.w * w0; a31 += iv.w * w1;
        }
        const float acc[4][2] = {{a00,a01},{a10,a11},{a20,a21},{a30,a31}};
        #pragma unroll
        for (int e = 0; e < 4; ++e) {
            const int n = nbase + e;
            h_new[n * 128 + ln]      = h[n * 128 + ln]      + acc[e][0];
            h_new[n * 128 + 64 + ln] = h[n * 128 + 64 + ln] + acc[e][1];
        }
        if (ln < 4) {
            const int n = nbase + ln;
            const float m = fmaxf(cnt[n], 1.0f);
            coord_new[n * 3 + 0] = coord[n * 3 + 0] + tsum[n * 3 + 0] / m;
            coord_new[n * 3 + 1] = coord[n * 3 + 1] + tsum[n * 3 + 1] / m;
            coord_new[n * 3 + 2] = coord[n * 3 + 2] + tsum[n * 3 + 2] / m;
        }
    }
}

extern "C" void kernel_launch(void* const* d_in, const int* in_sizes, int n_in,
                              void* d_out, int out_size, void* d_ws, size_t ws_size,
                              hipStream_t stream)
{
    const float* h     = (const float*)d_in[0];
    const float* coord = (const float*)d_in[1];
    const int*   ei    = (const int*)d_in[2];
    const float* w_e1  = (const float*)d_in[3];
    const float* b_e1  = (const float*)d_in[4];
    const float* w_e2  = (const float*)d_in[5];
    const float* b_e2  = (const float*)d_in[6];
    const float* w_n1  = (const float*)d_in[7];
    const float* b_n1  = (const float*)d_in[8];
    const float* w_n2  = (const float*)d_in[9];
    const float* b_n2  = (const float*)d_in[10];
    const float* w_c1  = (const float*)d_in[11];
    const float* b_c1  = (const float*)d_in[12];
    const float* w_c2  = (const float*)d_in[13];

    float* h_new     = (float*)d_out;
    float* coord_new = h_new + (size_t)NN * 128;
    float* ef        = coord_new + (size_t)NN * 3;   // edge_feat region (also t1 temp)

    float* agg  = (float*)d_ws;                      // [NN*128]
    float* tsum = agg + (size_t)NN * 128;            // [NN*3]
    float* cnt  = tsum + (size_t)NN * 3;             // [NN]
    float* u    = cnt + NN;                          // [NN*128]

    // zero the atomic accumulators (agg, tsum, cnt are contiguous)
    hipMemsetAsync(agg, 0, ((size_t)NN * 128 + (size_t)NN * 3 + NN) * sizeof(float), stream);

    k_edge_l1<<<256, 256, 0, stream>>>(h, coord, ei, w_e1, b_e1, ef);
    k_edge_l2<<<256, 256, 0, stream>>>(coord, ei, w_e2, b_e2, w_c1, b_c1, w_c2,
                                       ef, agg, tsum, cnt);
    k_node_l1<<<256, 256, 0, stream>>>(h, agg, w_n1, b_n1, u);
    k_node_l2<<<512, 256, 0, stream>>>(h, u, w_n2, b_n2, coord, tsum, cnt,
                                       h_new, coord_new);
}

// Round 2
// 550.366 us; speedup vs baseline: 5.3458x; 5.3458x over previous
//
#include <hip/hip_runtime.h>

#define NN 50000
#define NE 600000

typedef __attribute__((ext_vector_type(8))) short short8;
typedef __attribute__((ext_vector_type(4))) float f32x4;

__device__ __forceinline__ float silu_f(float x) { return x / (1.0f + __expf(-x)); }

__device__ __forceinline__ unsigned short f2bf(float f) {
    unsigned u = __builtin_bit_cast(unsigned, f);
    unsigned r = u + 0x7FFFu + ((u >> 16) & 1u);   // RNE
    return (unsigned short)(r >> 16);
}

// ---------------------------------------------------------------------------
// K0: h (fp32) -> h_bf16
// ---------------------------------------------------------------------------
__global__ __launch_bounds__(512) void k_prep(const float* __restrict__ h,
                                              unsigned short* __restrict__ hb)
{
    const int nchunks = NN * 128 / 8;   // 800000
    for (int i = blockIdx.x * blockDim.x + threadIdx.x; i < nchunks;
         i += gridDim.x * blockDim.x) {
        const float4* p = (const float4*)(h + (size_t)i * 8);
        float4 x = p[0], y = p[1];
        short8 v;
        v[0] = f2bf(x.x); v[1] = f2bf(x.y); v[2] = f2bf(x.z); v[3] = f2bf(x.w);
        v[4] = f2bf(y.x); v[5] = f2bf(y.y); v[6] = f2bf(y.z); v[7] = f2bf(y.w);
        *(short8*)(hb + (size_t)i * 8) = v;
    }
}

// ---------------------------------------------------------------------------
// K1: fused edge MLP.
//   t1 = silu([h[row],h[col],radial] @ w_e1 + b_e1)   (K=256 MFMA + rank-1 radial)
//   ef = silu(t1 @ w_e2 + b_e2)  -> d_out (fp32) + atomicAdd agg[row]
// Block: 512 thr = 8 waves (2M x 4N), tile = 64 edges. All tiles exact (NE%64==0).
// LDS: WT1 64KB, WT2 32KB, A1 32KB, A2 16KB (+rad/rows) = ~145KB -> 1 block/CU.
// ---------------------------------------------------------------------------
__global__ __launch_bounds__(512) void k_edge12(
    const unsigned short* __restrict__ hb, const float* __restrict__ coord,
    const int* __restrict__ ei,
    const float* __restrict__ w_e1, const float* __restrict__ b_e1,
    const float* __restrict__ w_e2, const float* __restrict__ b_e2,
    float* __restrict__ ef, float* __restrict__ agg)
{
    __shared__ unsigned short WT1[128 * 256];   // [n][k] swizzled, rowBytes=512
    __shared__ unsigned short WT2[128 * 128];   // [n][k] swizzled, rowBytes=256
    __shared__ unsigned short A1s[64 * 256];    // [e][k] swizzled, rowBytes=512
    __shared__ unsigned short A2s[64 * 128];    // [e][k] swizzled, rowBytes=256
    __shared__ float rad[64];
    __shared__ int rows_s[64];

    const int tid = threadIdx.x;
    const int wv = tid >> 6, lane = tid & 63;
    const int l4 = lane >> 4, li = lane & 15;
    const int mb = (wv >> 2) * 32;        // wave M-base (2 M-waves)
    const int nb = (wv & 3) * 32;         // wave N-base (4 N-waves)

    // stage weights once (w_e1 is [257][128] row-major; row 256 = radial weights)
    for (int i = tid; i < 257 * 128; i += 512) {
        int k = i >> 7, n = i & 127;
        if (k < 256) {
            int off = n * 512 + ((k * 2) ^ ((n & 7) << 4));
            *(unsigned short*)((char*)WT1 + off) = f2bf(w_e1[i]);
        }
    }
    for (int i = tid; i < 128 * 128; i += 512) {
        int k = i >> 7, n = i & 127;
        int off = n * 256 + ((k * 2) ^ ((n & 7) << 4));
        *(unsigned short*)((char*)WT2 + off) = f2bf(w_e2[i]);
    }
    float wradv[2], b1v[2], b2v[2];
    #pragma unroll
    for (int nf = 0; nf < 2; ++nf) {
        int n = nb + nf * 16 + li;
        wradv[nf] = w_e1[256 * 128 + n];
        b1v[nf]   = b_e1[n];
        b2v[nf]   = b_e2[n];
    }
    __syncthreads();

    const f32x4 z4 = {0.f, 0.f, 0.f, 0.f};

    for (int t = blockIdx.x; t < NE / 64; t += gridDim.x) {
        const int ebase = t * 64;
        // --- stage indices + radial ---
        if (tid < 64) {
            int e = ebase + tid;
            int r = ei[e], c = ei[NE + e];
            rows_s[tid] = r;
            float dx = coord[r * 3 + 0] - coord[c * 3 + 0];
            float dy = coord[r * 3 + 1] - coord[c * 3 + 1];
            float dz = coord[r * 3 + 2] - coord[c * 3 + 2];
            rad[tid] = dx * dx + dy * dy + dz * dz;
        }
        // --- stage A1: 64 edges x 32 chunks(16B) ---
        {
            int le = tid >> 3;
            int e = ebase + le;
            int r = ei[e], c = ei[NE + e];
            const unsigned short* hr = hb + (size_t)r * 128;
            const unsigned short* hc = hb + (size_t)c * 128;
            #pragma unroll
            for (int i = 0; i < 4; ++i) {
                int chunk = i * 8 + (tid & 7);
                short8 v = (chunk < 16) ? *(const short8*)(hr + chunk * 8)
                                        : *(const short8*)(hc + (chunk - 16) * 8);
                int off = le * 512 + ((chunk * 16) ^ ((le & 7) << 4));
                *(short8*)((char*)A1s + off) = v;
            }
        }
        __syncthreads();

        // --- GEMM1: K=256 ---
        f32x4 acc[2][2];
        acc[0][0] = z4; acc[0][1] = z4; acc[1][0] = z4; acc[1][1] = z4;
        for (int ks = 0; ks < 8; ++ks) {
            int kb = ks * 64 + l4 * 16;
            short8 af[2], bf[2];
            #pragma unroll
            for (int mf = 0; mf < 2; ++mf) {
                int row = mb + mf * 16 + li;
                af[mf] = *(const short8*)((const char*)A1s + row * 512 + (kb ^ ((row & 7) << 4)));
            }
            #pragma unroll
            for (int nf = 0; nf < 2; ++nf) {
                int row = nb + nf * 16 + li;
                bf[nf] = *(const short8*)((const char*)WT1 + row * 512 + (kb ^ ((row & 7) << 4)));
            }
            #pragma unroll
            for (int mf = 0; mf < 2; ++mf)
                #pragma unroll
                for (int nf = 0; nf < 2; ++nf)
                    acc[mf][nf] = __builtin_amdgcn_mfma_f32_16x16x32_bf16(
                        af[mf], bf[nf], acc[mf][nf], 0, 0, 0);
        }
        // epilogue1: + radial rank-1 + bias, silu, -> A2 (bf16, swizzled)
        #pragma unroll
        for (int mf = 0; mf < 2; ++mf)
            #pragma unroll
            for (int nf = 0; nf < 2; ++nf)
                #pragma unroll
                for (int r = 0; r < 4; ++r) {
                    int row = mb + mf * 16 + l4 * 4 + r;
                    float v = acc[mf][nf][r] + rad[row] * wradv[nf] + b1v[nf];
                    v = silu_f(v);
                    int colb = (nb + nf * 16 + li) * 2;
                    int off = row * 256 + (colb ^ ((row & 7) << 4));
                    *(unsigned short*)((char*)A2s + off) = f2bf(v);
                }
        __syncthreads();

        // --- GEMM2: K=128 ---
        f32x4 acc2[2][2];
        acc2[0][0] = z4; acc2[0][1] = z4; acc2[1][0] = z4; acc2[1][1] = z4;
        for (int ks = 0; ks < 4; ++ks) {
            int kb = ks * 64 + l4 * 16;
            short8 af[2], bf[2];
            #pragma unroll
            for (int mf = 0; mf < 2; ++mf) {
                int row = mb + mf * 16 + li;
                af[mf] = *(const short8*)((const char*)A2s + row * 256 + (kb ^ ((row & 7) << 4)));
            }
            #pragma unroll
            for (int nf = 0; nf < 2; ++nf) {
                int row = nb + nf * 16 + li;
                bf[nf] = *(const short8*)((const char*)WT2 + row * 256 + (kb ^ ((row & 7) << 4)));
            }
            #pragma unroll
            for (int mf = 0; mf < 2; ++mf)
                #pragma unroll
                for (int nf = 0; nf < 2; ++nf)
                    acc2[mf][nf] = __builtin_amdgcn_mfma_f32_16x16x32_bf16(
                        af[mf], bf[nf], acc2[mf][nf], 0, 0, 0);
        }
        // epilogue2: silu, store ef (fp32), atomic agg
        #pragma unroll
        for (int mf = 0; mf < 2; ++mf)
            #pragma unroll
            for (int nf = 0; nf < 2; ++nf)
                #pragma unroll
                for (int r = 0; r < 4; ++r) {
                    int row = mb + mf * 16 + l4 * 4 + r;
                    int e = ebase + row;
                    int col = nb + nf * 16 + li;
                    float v = silu_f(acc2[mf][nf][r] + b2v[nf]);
                    ef[(size_t)e * 128 + col] = v;
                    atomicAdd(&agg[(size_t)rows_s[row] * 128 + col], v);
                }
        __syncthreads();   // protect A1/A2/rad/rows before next tile
    }
}

// ---------------------------------------------------------------------------
// K2: coord MLP.  wq = silu(ef @ w_c1 + b_c1) @ w_c2  (per-edge scalar)
//     atomics: tsum[row] += coord_diff * wq ; cnt[row] += 1
// Block: 512 thr = 8 waves (8M x 1N), tile = 128 edges (tail-guarded).
// ---------------------------------------------------------------------------
__global__ __launch_bounds__(512) void k_coord(
    const float* __restrict__ ef, const float* __restrict__ coord,
    const int* __restrict__ ei,
    const float* __restrict__ w_c1, const float* __restrict__ b_c1,
    const float* __restrict__ w_c2,
    float* __restrict__ tsum, float* __restrict__ cnt)
{
    __shared__ unsigned short Aefs[128 * 128];  // [e][k] swizzled, rowBytes=256
    __shared__ unsigned short WTc[128 * 128];   // [n][k] swizzled, rowBytes=256

    const int tid = threadIdx.x;
    const int wv = tid >> 6, lane = tid & 63;
    const int l4 = lane >> 4, li = lane & 15;

    for (int i = tid; i < 128 * 128; i += 512) {
        int k = i >> 7, n = i & 127;
        int off = n * 256 + ((k * 2) ^ ((n & 7) << 4));
        *(unsigned short*)((char*)WTc + off) = f2bf(w_c1[i]);
    }
    float bc1v[8], wc2v[8];
    #pragma unroll
    for (int nf = 0; nf < 8; ++nf) {
        bc1v[nf] = b_c1[nf * 16 + li];
        wc2v[nf] = w_c2[nf * 16 + li];
    }
    __syncthreads();

    const f32x4 z4 = {0.f, 0.f, 0.f, 0.f};
    const int ntiles = (NE + 127) / 128;

    for (int t = blockIdx.x; t < ntiles; t += gridDim.x) {
        const int ebase = t * 128;
        // stage A from ef fp32 (coalesced), guard tail
        {
            int le = tid >> 2;
            int e = ebase + le;
            #pragma unroll
            for (int i = 0; i < 4; ++i) {
                int chunk = i * 4 + (tid & 3);
                short8 v;
                if (e < NE) {
                    const float4* p = (const float4*)(ef + (size_t)e * 128 + chunk * 8);
                    float4 x = p[0], y = p[1];
                    v[0] = f2bf(x.x); v[1] = f2bf(x.y); v[2] = f2bf(x.z); v[3] = f2bf(x.w);
                    v[4] = f2bf(y.x); v[5] = f2bf(y.y); v[6] = f2bf(y.z); v[7] = f2bf(y.w);
                } else {
                    v = (short8)0;
                }
                int off = le * 256 + ((chunk * 16) ^ ((le & 7) << 4));
                *(short8*)((char*)Aefs + off) = v;
            }
        }
        __syncthreads();

        f32x4 acc[8];
        #pragma unroll
        for (int nf = 0; nf < 8; ++nf) acc[nf] = z4;
        const int mrow = wv * 16 + li;
        for (int ks = 0; ks < 4; ++ks) {
            int kb = ks * 64 + l4 * 16;
            short8 a = *(const short8*)((const char*)Aefs + mrow * 256 + (kb ^ ((mrow & 7) << 4)));
            #pragma unroll
            for (int nf = 0; nf < 8; ++nf) {
                int row = nf * 16 + li;
                short8 b = *(const short8*)((const char*)WTc + row * 256 + (kb ^ ((row & 7) << 4)));
                acc[nf] = __builtin_amdgcn_mfma_f32_16x16x32_bf16(a, b, acc[nf], 0, 0, 0);
            }
        }
        // wq per row: silu(c1)@w_c2, reduce across 16 lanes
        float wq[4];
        #pragma unroll
        for (int r = 0; r < 4; ++r) {
            float p = 0.f;
            #pragma unroll
            for (int nf = 0; nf < 8; ++nf)
                p += silu_f(acc[nf][r] + bc1v[nf]) * wc2v[nf];
            #pragma unroll
            for (int off = 1; off < 16; off <<= 1) p += __shfl_xor(p, off);
            wq[r] = p;
        }
        if (li == 0) {
            #pragma unroll
            for (int r = 0; r < 4; ++r) {
                int e = ebase + wv * 16 + l4 * 4 + r;
                if (e < NE) {
                    int rr = ei[e], cc = ei[NE + e];
                    float dx = coord[rr * 3 + 0] - coord[cc * 3 + 0];
                    float dy = coord[rr * 3 + 1] - coord[cc * 3 + 1];
                    float dz = coord[rr * 3 + 2] - coord[cc * 3 + 2];
                    atomicAdd(&tsum[rr * 3 + 0], dx * wq[r]);
                    atomicAdd(&tsum[rr * 3 + 1], dy * wq[r]);
                    atomicAdd(&tsum[rr * 3 + 2], dz * wq[r]);
                    atomicAdd(&cnt[rr], 1.0f);
                }
            }
        }
        __syncthreads();
    }
}

// ---------------------------------------------------------------------------
// K3: u = silu([h, agg] @ w_n1 + b_n1)  -> u_bf16
// Block: 512 thr = 8 waves (2M x 4N), tile = 128 nodes (tail-guarded).
// ---------------------------------------------------------------------------
__global__ __launch_bounds__(512) void k_node1(
    const unsigned short* __restrict__ hb, const float* __restrict__ agg,
    const float* __restrict__ w_n1, const float* __restrict__ b_n1,
    unsigned short* __restrict__ ub)
{
    __shared__ unsigned short WT[128 * 256];    // [n][k] rowBytes=512
    __shared__ unsigned short As[128 * 256];    // [node][k] rowBytes=512

    const int tid = threadIdx.x;
    const int wv = tid >> 6, lane = tid & 63;
    const int l4 = lane >> 4, li = lane & 15;
    const int mb = (wv >> 2) * 64;
    const int nb = (wv & 3) * 32;

    for (int i = tid; i < 256 * 128; i += 512) {
        int k = i >> 7, n = i & 127;
        int off = n * 512 + ((k * 2) ^ ((n & 7) << 4));
        *(unsigned short*)((char*)WT + off) = f2bf(w_n1[i]);
    }
    float b1v[2];
    #pragma unroll
    for (int nf = 0; nf < 2; ++nf) b1v[nf] = b_n1[nb + nf * 16 + li];
    __syncthreads();

    const f32x4 z4 = {0.f, 0.f, 0.f, 0.f};
    const int ntiles = (NN + 127) / 128;

    for (int t = blockIdx.x; t < ntiles; t += gridDim.x) {
        const int nbase = t * 128;
        {
            int ln = tid >> 2;
            int node = nbase + ln;
            #pragma unroll
            for (int i = 0; i < 8; ++i) {
                int chunk = i * 4 + (tid & 3);
                short8 v;
                if (node < NN) {
                    if (chunk < 16) {
                        v = *(const short8*)(hb + (size_t)node * 128 + chunk * 8);
                    } else {
                        const float4* p = (const float4*)(agg + (size_t)node * 128 + (chunk - 16) * 8);
                        float4 x = p[0], y = p[1];
                        v[0] = f2bf(x.x); v[1] = f2bf(x.y); v[2] = f2bf(x.z); v[3] = f2bf(x.w);
                        v[4] = f2bf(y.x); v[5] = f2bf(y.y); v[6] = f2bf(y.z); v[7] = f2bf(y.w);
                    }
                } else v = (short8)0;
                int off = ln * 512 + ((chunk * 16) ^ ((ln & 7) << 4));
                *(short8*)((char*)As + off) = v;
            }
        }
        __syncthreads();

        f32x4 acc[4][2];
        #pragma unroll
        for (int mf = 0; mf < 4; ++mf) { acc[mf][0] = z4; acc[mf][1] = z4; }
        for (int ks = 0; ks < 8; ++ks) {
            int kb = ks * 64 + l4 * 16;
            short8 af[4], bf[2];
            #pragma unroll
            for (int mf = 0; mf < 4; ++mf) {
                int row = mb + mf * 16 + li;
                af[mf] = *(const short8*)((const char*)As + row * 512 + (kb ^ ((row & 7) << 4)));
            }
            #pragma unroll
            for (int nf = 0; nf < 2; ++nf) {
                int row = nb + nf * 16 + li;
                bf[nf] = *(const short8*)((const char*)WT + row * 512 + (kb ^ ((row & 7) << 4)));
            }
            #pragma unroll
            for (int mf = 0; mf < 4; ++mf)
                #pragma unroll
                for (int nf = 0; nf < 2; ++nf)
                    acc[mf][nf] = __builtin_amdgcn_mfma_f32_16x16x32_bf16(
                        af[mf], bf[nf], acc[mf][nf], 0, 0, 0);
        }
        #pragma unroll
        for (int mf = 0; mf < 4; ++mf)
            #pragma unroll
            for (int nf = 0; nf < 2; ++nf)
                #pragma unroll
                for (int r = 0; r < 4; ++r) {
                    int row = mb + mf * 16 + l4 * 4 + r;
                    int node = nbase + row;
                    if (node < NN) {
                        float v = silu_f(acc[mf][nf][r] + b1v[nf]);
                        ub[(size_t)node * 128 + nb + nf * 16 + li] = f2bf(v);
                    }
                }
        __syncthreads();
    }
}

// ---------------------------------------------------------------------------
// K4: h_new = h + u @ w_n2 + b_n2 ;  coord_new = coord + tsum / max(cnt,1)
// Block: 512 thr = 8 waves (8M x 1N), tile = 128 nodes (tail-guarded).
// ---------------------------------------------------------------------------
__global__ __launch_bounds__(512) void k_node2(
    const float* __restrict__ h, const unsigned short* __restrict__ ub,
    const float* __restrict__ w_n2, const float* __restrict__ b_n2,
    const float* __restrict__ coord, const float* __restrict__ tsum,
    const float* __restrict__ cnt,
    float* __restrict__ h_new, float* __restrict__ coord_new)
{
    __shared__ unsigned short Aus[128 * 128];   // rowBytes=256
    __shared__ unsigned short WT[128 * 128];    // rowBytes=256

    const int tid = threadIdx.x;
    const int wv = tid >> 6, lane = tid & 63;
    const int l4 = lane >> 4, li = lane & 15;

    for (int i = tid; i < 128 * 128; i += 512) {
        int k = i >> 7, n = i & 127;
        int off = n * 256 + ((k * 2) ^ ((n & 7) << 4));
        *(unsigned short*)((char*)WT + off) = f2bf(w_n2[i]);
    }
    float b2v[8];
    #pragma unroll
    for (int nf = 0; nf < 8; ++nf) b2v[nf] = b_n2[nf * 16 + li];
    __syncthreads();

    const f32x4 z4 = {0.f, 0.f, 0.f, 0.f};
    const int ntiles = (NN + 127) / 128;

    for (int t = blockIdx.x; t < ntiles; t += gridDim.x) {
        const int nbase = t * 128;
        {
            int ln = tid >> 2;
            int node = nbase + ln;
            #pragma unroll
            for (int i = 0; i < 4; ++i) {
                int chunk = i * 4 + (tid & 3);
                short8 v;
                if (node < NN) v = *(const short8*)(ub + (size_t)node * 128 + chunk * 8);
                else v = (short8)0;
                int off = ln * 256 + ((chunk * 16) ^ ((ln & 7) << 4));
                *(short8*)((char*)Aus + off) = v;
            }
        }
        __syncthreads();

        f32x4 acc[8];
        #pragma unroll
        for (int nf = 0; nf < 8; ++nf) acc[nf] = z4;
        const int mrow = wv * 16 + li;
        for (int ks = 0; ks < 4; ++ks) {
            int kb = ks * 64 + l4 * 16;
            short8 a = *(const short8*)((const char*)Aus + mrow * 256 + (kb ^ ((mrow & 7) << 4)));
            #pragma unroll
            for (int nf = 0; nf < 8; ++nf) {
                int row = nf * 16 + li;
                short8 b = *(const short8*)((const char*)WT + row * 256 + (kb ^ ((row & 7) << 4)));
                acc[nf] = __builtin_amdgcn_mfma_f32_16x16x32_bf16(a, b, acc[nf], 0, 0, 0);
            }
        }
        #pragma unroll
        for (int nf = 0; nf < 8; ++nf)
            #pragma unroll
            for (int r = 0; r < 4; ++r) {
                int row = wv * 16 + l4 * 4 + r;
                int node = nbase + row;
                if (node < NN) {
                    int col = nf * 16 + li;
                    float v = acc[nf][r] + b2v[nf] + h[(size_t)node * 128 + col];
                    h_new[(size_t)node * 128 + col] = v;
                }
            }
        if (tid < 128) {
            int node = nbase + tid;
            if (node < NN) {
                float m = fmaxf(cnt[node], 1.0f);
                coord_new[node * 3 + 0] = coord[node * 3 + 0] + tsum[node * 3 + 0] / m;
                coord_new[node * 3 + 1] = coord[node * 3 + 1] + tsum[node * 3 + 1] / m;
                coord_new[node * 3 + 2] = coord[node * 3 + 2] + tsum[node * 3 + 2] / m;
            }
        }
        __syncthreads();
    }
}

extern "C" void kernel_launch(void* const* d_in, const int* in_sizes, int n_in,
                              void* d_out, int out_size, void* d_ws, size_t ws_size,
                              hipStream_t stream)
{
    const float* h     = (const float*)d_in[0];
    const float* coord = (const float*)d_in[1];
    const int*   ei    = (const int*)d_in[2];
    const float* w_e1  = (const float*)d_in[3];
    const float* b_e1  = (const float*)d_in[4];
    const float* w_e2  = (const float*)d_in[5];
    const float* b_e2  = (const float*)d_in[6];
    const float* w_n1  = (const float*)d_in[7];
    const float* b_n1  = (const float*)d_in[8];
    const float* w_n2  = (const float*)d_in[9];
    const float* b_n2  = (const float*)d_in[10];
    const float* w_c1  = (const float*)d_in[11];
    const float* b_c1  = (const float*)d_in[12];
    const float* w_c2  = (const float*)d_in[13];

    float* h_new     = (float*)d_out;
    float* coord_new = h_new + (size_t)NN * 128;
    float* ef        = coord_new + (size_t)NN * 3;

    // ws layout (52.0 MB total, same footprint as round 1)
    float*          agg  = (float*)d_ws;                      // [NN*128] f32
    float*          tsum = agg + (size_t)NN * 128;            // [NN*3]
    float*          cnt  = tsum + (size_t)NN * 3;             // [NN]
    unsigned short* hb   = (unsigned short*)(cnt + NN);       // [NN*128] bf16
    unsigned short* ub   = hb + (size_t)NN * 128;             // [NN*128] bf16

    hipMemsetAsync(agg, 0, ((size_t)NN * 128 + (size_t)NN * 3 + NN) * sizeof(float), stream);

    k_prep  <<<1024, 512, 0, stream>>>(h, hb);
    k_edge12<<<256,  512, 0, stream>>>(hb, coord, ei, w_e1, b_e1, w_e2, b_e2, ef, agg);
    k_coord <<<512,  512, 0, stream>>>(ef, coord, ei, w_c1, b_c1, w_c2, tsum, cnt);
    k_node1 <<<391,  512, 0, stream>>>(hb, agg, w_n1, b_n1, ub);
    k_node2 <<<391,  512, 0, stream>>>(h, ub, w_n2, b_n2, coord, tsum, cnt, h_new, coord_new);
}